// Round 1
// baseline (16.430 us; speedup 1.0000x reference)
//
#include <hip/hip_runtime.h>

// QuantumSelfAttention: analytic reduction.
// P(|1> on qubit 0) after Ry layer + CRX ladder (controls never rotated by a
// non-diagonal op on qubit 0) == sin^2(theta0 / 2), theta0 = features[b,n,0].
// D = 64 floats per row; we need only element 0 of each row (stride 256 B).

__global__ __launch_bounds__(256) void qsa_p1_kernel(
    const float* __restrict__ feat, float* __restrict__ out, int n) {
    int i = blockIdx.x * blockDim.x + threadIdx.x;
    if (i < n) {
        float th = feat[(size_t)i * 64];
        float s = __sinf(0.5f * th);
        out[i] = s * s;
    }
}

extern "C" void kernel_launch(void* const* d_in, const int* in_sizes, int n_in,
                              void* d_out, int out_size, void* d_ws, size_t ws_size,
                              hipStream_t stream) {
    const float* feat = (const float*)d_in[0];   // [64, 8192, 64] f32
    float* out = (float*)d_out;                  // [64, 8192] f32
    int n = out_size;                            // 524288
    const int threads = 256;
    int blocks = (n + threads - 1) / threads;    // 2048
    qsa_p1_kernel<<<blocks, threads, 0, stream>>>(feat, out, n);
}

// Round 2
// 13.686 us; speedup vs baseline: 1.2005x; 1.2005x over previous
//
#include <hip/hip_runtime.h>

// QuantumSelfAttention: analytic reduction.
// P(|1> on qubit 0) = sin^2(theta0/2), theta0 = features[b,n,0] (row stride 64 f32).
// Pure strided gather: 1 float per 256 B. 4 rows/thread for MLP; nt loads
// (read-once stream, skip L2 allocation).

__global__ __launch_bounds__(256) void qsa_p1_kernel(
    const float* __restrict__ feat, float* __restrict__ out, int n) {
    // Each block handles 1024 consecutive rows: 4 chunks of 256 (one per lane).
    int base = blockIdx.x * 1024 + threadIdx.x;
    float th0 = __builtin_nontemporal_load(feat + (size_t)(base        ) * 64);
    float th1 = __builtin_nontemporal_load(feat + (size_t)(base +  256 ) * 64);
    float th2 = __builtin_nontemporal_load(feat + (size_t)(base +  512 ) * 64);
    float th3 = __builtin_nontemporal_load(feat + (size_t)(base +  768 ) * 64);
    float s0 = __sinf(0.5f * th0);
    float s1 = __sinf(0.5f * th1);
    float s2 = __sinf(0.5f * th2);
    float s3 = __sinf(0.5f * th3);
    out[base]       = s0 * s0;
    out[base + 256] = s1 * s1;
    out[base + 512] = s2 * s2;
    out[base + 768] = s3 * s3;
}

extern "C" void kernel_launch(void* const* d_in, const int* in_sizes, int n_in,
                              void* d_out, int out_size, void* d_ws, size_t ws_size,
                              hipStream_t stream) {
    const float* feat = (const float*)d_in[0];   // [64, 8192, 64] f32
    float* out = (float*)d_out;                  // [64, 8192] f32
    int n = out_size;                            // 524288 (multiple of 1024)
    const int threads = 256;
    int blocks = n / 1024;                       // 512
    qsa_p1_kernel<<<blocks, threads, 0, stream>>>(feat, out, n);
}